// Round 7
// baseline (180.167 us; speedup 1.0000x reference)
//
#include <hip/hip_runtime.h>
#include <hip/hip_bf16.h>
#include <stdint.h>

// B=16, D=64, S=2048
// scores[b,s,t] = dot(q[b,:,s],k[b,:,t])/8 ; mask -> -1000 ; softmax over s
// (query axis) ; out[b,s,d] = sum_t attn[b,s,t] v[b,d,t].
// |score|<~6: p = mask?0:exp(score/8); l[t]=sum_s p; out = (p/l) @ V^T.
//
// Round-7: barrier-aware pipelining. __syncthreads drains vmcnt(0), so all
// VMEM issues are placed AFTER the last barrier of an iteration and consumed
// after the first barrier of the next, with MFMA phases covering the latency.
//   prep (1 kernel): q,k transpose-cvt -> bf16 [b][x][d]; v straight cvt
//   pass1: MFMA colsums + inline mask pack (qsb dbuf, reg-prefetched mask)
//   linv; pass2 (t-split x2, K/V/meta dbuf): swapped QK^T + P tile + PV MFMA
//   opart reduce.
// Tiers by ws_size: >=38.4MB full; >=21.6MB unsplit pass2; >=13.2MB round-3
// path; else fp32 fallback.

namespace {
constexpr int B = 16;
constexpr int D = 64;
constexpr int S = 2048;
constexpr float SCALE = 0.125f;

typedef __attribute__((ext_vector_type(8))) short short8; // 8 bf16
typedef __attribute__((ext_vector_type(4))) float f32x4;

constexpr size_t WS_FLAG  = 0;
constexpr size_t WS_LINV  = 256;                    // B*S f32
constexpr size_t WS_LPART = 256 + 131072;           // 4*B*S f32
constexpr size_t WS_QT    = 655616;                 // B*S*D bf16 = 4MB
constexpr size_t WS_KT    = 4849920;
constexpr size_t WS_VB    = 9044224;
constexpr size_t WS_MPACK = 13238528;               // B*(S/64)*S u64 = 8MB
constexpr size_t WS_OPART = 21627136;               // 2 * B*S*D f32 = 16MB
constexpr size_t NEED_OLD = 13238528;
constexpr size_t NEED_T1  = 21627136;
constexpr size_t NEED_T2  = 38404352;
}

__device__ __forceinline__ bool mask_at(const void* mask, int mode, size_t idx) {
    if (mode == 1) return ((const int*)mask)[idx] != 0;
    if (mode == 2) return ((const float*)mask)[idx] != 0.0f;
    return ((const unsigned char*)mask)[idx] != 0;
}

__device__ __forceinline__ uint16_t f2bf(float f) {
    unsigned int u = __float_as_uint(f);
    unsigned int r = (u + 0x7fffu + ((u >> 16) & 1u)) >> 16;
    return (uint16_t)r;
}
__device__ __forceinline__ unsigned int pack2(float a, float b) {
    return (unsigned int)f2bf(a) | ((unsigned int)f2bf(b) << 16);
}

// swizzled LDS byte address for 64x64-bf16 tiles stored as 128B rows
__device__ __forceinline__ int swz(int row, int colByte) {
    return row * 128 + (colByte ^ ((row & 7) << 4));
}

__device__ __forceinline__ void gll16(const void* g, void* l) {
    __builtin_amdgcn_global_load_lds(
        (const __attribute__((address_space(1))) void*)g,
        (__attribute__((address_space(3))) void*)l, 16, 0, 0);
}

// Stage a 64-row x 128B tile; LDS linear dest, source pre-swizzled.
__device__ __forceinline__ void stage_tile(const char* srcRows, size_t rowStrideB,
                                           unsigned char* dst, int tid) {
    const int lane = tid & 63, w = tid >> 6;
    const int lrow = lane >> 3;
    const int slot = (lane & 7) ^ lrow;
    #pragma unroll
    for (int c = 0; c < 2; ++c) {
        const int row = 16 * w + 8 * c + lrow;
        gll16(srcRows + (size_t)row * rowStrideB + slot * 16,
              dst + (16 * w + 8 * c) * 128);
    }
}

__device__ __forceinline__ f32x4 mfma16(short8 a, short8 b, f32x4 c) {
    return __builtin_amdgcn_mfma_f32_16x16x32_bf16(a, b, c, 0, 0, 0);
}

// ---------------------------------------------------------------------------
// k0: classify mask element width from byte pattern (first 64KB).
// ---------------------------------------------------------------------------
__global__ void probe_mask_kernel(const unsigned char* __restrict__ mask,
                                  int* __restrict__ flag)
{
    __shared__ int c0s, c123s;
    if (threadIdx.x == 0) { c0s = 0; c123s = 0; }
    __syncthreads();
    int c0 = 0, c123 = 0;
    for (int f = threadIdx.x; f < 65536; f += 256) {
        const int nz = (mask[f] != 0) ? 1 : 0;
        if ((f & 3) == 0) c0 += nz; else c123 += nz;
    }
    atomicAdd(&c0s, c0);
    atomicAdd(&c123s, c123);
    __syncthreads();
    if (threadIdx.x == 0) {
        int mode = 0;
        if (c123s == 0) mode = 1;
        else if (c0s == 0) mode = 2;
        *flag = mode;
    }
}

// ---------------------------------------------------------------------------
// prep: z=0 -> q->qT (transpose+cvt), z=1 -> k->kT, z=2 -> v->vb (straight cvt)
// ---------------------------------------------------------------------------
__global__ __launch_bounds__(256, 2)
void prep_kernel(const float* __restrict__ q, const float* __restrict__ k,
                 const float* __restrict__ v,
                 uint16_t* __restrict__ qT, uint16_t* __restrict__ kT,
                 uint16_t* __restrict__ vb)
{
    __shared__ float ts[64][65];
    const int tid = threadIdx.x;
    const int s0 = blockIdx.x * 64;
    const int b  = blockIdx.y;

    if (blockIdx.z == 2) {
        const int d = tid >> 2, c = tid & 3;
        const float* row = v + ((size_t)b * D + d) * S + s0 + c * 16;
        uint16_t*   orow = vb + ((size_t)b * D + d) * S + s0 + c * 16;
        #pragma unroll
        for (int i = 0; i < 4; ++i) {
            float4 v4 = *(const float4*)(row + 4 * i);
            uint16_t t4[4] = {f2bf(v4.x), f2bf(v4.y), f2bf(v4.z), f2bf(v4.w)};
            *(uint2*)(orow + 4 * i) = *(const uint2*)t4;
        }
        return;
    }

    const float* src = blockIdx.z ? k : q;
    uint16_t*    dst = blockIdx.z ? kT : qT;
    {
        const int d = tid >> 2, c = tid & 3;
        const float* row = src + ((size_t)b * D + d) * S + s0 + c * 16;
        #pragma unroll
        for (int i = 0; i < 4; ++i) {
            float4 v4 = *(const float4*)(row + 4 * i);
            ts[c * 16 + 4 * i + 0][d] = v4.x;
            ts[c * 16 + 4 * i + 1][d] = v4.y;
            ts[c * 16 + 4 * i + 2][d] = v4.z;
            ts[c * 16 + 4 * i + 3][d] = v4.w;
        }
    }
    __syncthreads();
    {
        const int srow = tid >> 2, p = tid & 3;
        uint16_t tmp[16];
        #pragma unroll
        for (int j = 0; j < 16; ++j) tmp[j] = f2bf(ts[srow][p * 16 + j]);
        uint16_t* drow = dst + ((size_t)b * S + s0 + srow) * 64 + p * 16;
        *(uint4*)drow       = ((const uint4*)tmp)[0];
        *((uint4*)drow + 1) = ((const uint4*)tmp)[1];
    }
}

// ---------------------------------------------------------------------------
// pass1: MFMA colsums + inline streaming mask pack; barrier-aware pipeline.
// grid (S/64, 4, B). Loop invariant: all VMEM for iter it+1 (qsb staging,
// mask reg loads) is issued AFTER the mid barrier of iter it and covered by
// iter it's MFMA phase; the top barrier of it+1 drains it.
// ---------------------------------------------------------------------------
__global__ __launch_bounds__(256, 4)
void pass1_kernel(const uint16_t* __restrict__ qT, const uint16_t* __restrict__ kT,
                  const void* __restrict__ mask, const int* __restrict__ flagp,
                  float* __restrict__ lpart, unsigned long long* __restrict__ mpackT)
{
    __shared__ __align__(16) unsigned char ksb[64 * 128];
    __shared__ __align__(16) unsigned char qsb[2][64 * 128];
    __shared__ unsigned short mbits[64][4]; // [s_row][t_quarter]
    __shared__ float red[4][64];

    const int tid = threadIdx.x;
    const int lane = tid & 63, w = tid >> 6;
    const int l = lane & 15, hh = lane >> 4;
    const int t0 = blockIdx.x * 64;
    const int chunk = blockIdx.y;
    const int b = blockIdx.z;
    const int mode = *flagp;

    const int row_m = tid >> 2, cq = tid & 3;
    const size_t mrow_base = ((size_t)b * S + row_m) * S + t0 + cq * 16; // + sbase*S

    int4  mr4[4]; // 4B-element modes (i32 / f32-as-bits)
    uint4 mr1;    // 1B-element mode
    auto load_mtile = [&](int sbase) {
        if (mode != 0) {
            const int4* p = (const int4*)((const int*)mask + mrow_base + (size_t)sbase * S);
            mr4[0] = p[0]; mr4[1] = p[1]; mr4[2] = p[2]; mr4[3] = p[3];
        } else {
            mr1 = *(const uint4*)((const unsigned char*)mask + mrow_base + (size_t)sbase * S);
        }
    };
    auto pack_mtile = [&]() -> unsigned int {
        unsigned int bits = 0;
        if (mode != 0) {
            #pragma unroll
            for (int i = 0; i < 4; ++i) {
                bits |= (mr4[i].x ? 1u : 0u) << (4 * i + 0);
                bits |= (mr4[i].y ? 1u : 0u) << (4 * i + 1);
                bits |= (mr4[i].z ? 1u : 0u) << (4 * i + 2);
                bits |= (mr4[i].w ? 1u : 0u) << (4 * i + 3);
            }
        } else {
            const unsigned int u[4] = {mr1.x, mr1.y, mr1.z, mr1.w};
            #pragma unroll
            for (int c = 0; c < 4; ++c) {
                bits |= ((u[c] & 0x000000FFu) ? 1u : 0u) << (4 * c + 0);
                bits |= ((u[c] & 0x0000FF00u) ? 1u : 0u) << (4 * c + 1);
                bits |= ((u[c] & 0x00FF0000u) ? 1u : 0u) << (4 * c + 2);
                bits |= ((u[c] & 0xFF000000u) ? 1u : 0u) << (4 * c + 3);
            }
        }
        return bits;
    };

    // prologue: issue everything for it=0
    stage_tile((const char*)(kT + ((size_t)b * S + t0) * 64), 128, ksb, tid);
    stage_tile((const char*)(qT + ((size_t)b * S + chunk * 512) * 64), 128, qsb[0], tid);
    load_mtile(chunk * 512);

    float colacc[4] = {0.f, 0.f, 0.f, 0.f};

    for (int it = 0; it < 8; ++it) {
        const int cur = it & 1;
        const int sbase = chunk * 512 + it * 64;

        __syncthreads(); // TOP: drains staging+mask loads issued last iter (covered by MFMA)

        const unsigned int bits = pack_mtile(); // regs are ready (drained at TOP)
        mbits[row_m][cq] = (unsigned short)bits;

        __syncthreads(); // MID: mbits visible; no VMEM issued since TOP -> cheap

        // coalesced packed-mask writeout (512B per block-iteration)
        if (tid < 64) {
            const unsigned long long word =
                (unsigned long long)mbits[tid][0]
                | ((unsigned long long)mbits[tid][1] << 16)
                | ((unsigned long long)mbits[tid][2] << 32)
                | ((unsigned long long)mbits[tid][3] << 48);
            mpackT[((size_t)b * 32 + (t0 >> 6)) * S + sbase + tid] = word;
        }

        // issue next tile's VMEM now; MFMA phase below covers the latency
        if (it < 7) {
            stage_tile((const char*)(qT + ((size_t)b * S + sbase + 64) * 64), 128,
                       qsb[cur ^ 1], tid);
            load_mtile(sbase + 64);
        }

        // MFMA phase (reads qsb[cur], ksb, mbits — all LDS/regs)
        short8 A0 = *(const short8*)&qsb[cur][swz(16 * w + l, 0  + hh * 16)];
        short8 A1 = *(const short8*)&qsb[cur][swz(16 * w + l, 64 + hh * 16)];
        const int srow_l = 16 * w + 4 * hh;

        #pragma unroll
        for (int tf = 0; tf < 4; ++tf) {
            const short8 B0 = *(const short8*)&ksb[swz(tf * 16 + l, 0  + hh * 16)];
            const short8 B1 = *(const short8*)&ksb[swz(tf * 16 + l, 64 + hh * 16)];
            f32x4 c4 = {0.f, 0.f, 0.f, 0.f};
            c4 = mfma16(A0, B0, c4);
            c4 = mfma16(A1, B1, c4);
            #pragma unroll
            for (int r = 0; r < 4; ++r) {
                if (!((mbits[srow_l + r][tf] >> l) & 1))
                    colacc[tf] += __expf(c4[r] * SCALE);
            }
        }
    }

    #pragma unroll
    for (int tf = 0; tf < 4; ++tf) {
        colacc[tf] += __shfl_xor(colacc[tf], 16);
        colacc[tf] += __shfl_xor(colacc[tf], 32);
    }
    __syncthreads();
    if (lane < 16) {
        #pragma unroll
        for (int tf = 0; tf < 4; ++tf) red[w][tf * 16 + lane] = colacc[tf];
    }
    __syncthreads();
    if (tid < 64) {
        const float s = red[0][tid] + red[1][tid] + red[2][tid] + red[3][tid];
        lpart[(size_t)chunk * (B * S) + (size_t)b * S + t0 + tid] = s;
    }
}

__global__ void linv_kernel(const float* __restrict__ lpart, float* __restrict__ linv)
{
    const int i = blockIdx.x * 256 + threadIdx.x;
    const float s = lpart[i] + lpart[B * S + i] + lpart[2 * B * S + i] + lpart[3 * B * S + i];
    linv[i] = 1.0f / s;
}

// ---------------------------------------------------------------------------
// pass2: grid (S/64, NCHUNK, B); t in [tc*tspan, +tspan). K/V/meta double-
// buffered: staging for tile i+1 is issued inside phase B of tile i (after
// the A->B barrier), covered by B's MFMAs, drained at the loop-end barrier.
// ---------------------------------------------------------------------------
__global__ __launch_bounds__(256, 2)
void pass2_kernel(const uint16_t* __restrict__ qT, const uint16_t* __restrict__ kT,
                  const uint16_t* __restrict__ vb,
                  const unsigned long long* __restrict__ mpackT,
                  const float* __restrict__ linv, float* __restrict__ dst, int tspan)
{
    __shared__ __align__(16) unsigned char qsb[64 * 128];
    __shared__ __align__(16) unsigned char ksb[2][64 * 128];
    __shared__ __align__(16) unsigned char vsb[2][64 * 128];
    __shared__ __align__(16) unsigned char ptb[64 * 128];
    __shared__ unsigned long long mrow2[2][64];
    __shared__ float linv_s[2][64];

    const int tid = threadIdx.x;
    const int lane = tid & 63, w = tid >> 6;
    const int l = lane & 15, hh = lane >> 4;
    const int s0 = blockIdx.x * 64;
    const int tc = blockIdx.y;
    const int b = blockIdx.z;
    const int t_begin = tc * tspan;
    const int niter = tspan / 64;
    float* outp = dst + (size_t)tc * (B * S * D);

    // prologue: Q tile + first K/V/meta
    stage_tile((const char*)(qT + ((size_t)b * S + s0) * 64), 128, qsb, tid);
    stage_tile((const char*)(kT + ((size_t)b * S + t_begin) * 64), 128, ksb[0], tid);
    stage_tile((const char*)(vb + (size_t)b * D * S + t_begin), (size_t)S * 2, vsb[0], tid);
    if (tid < 64) {
        mrow2[0][tid]  = mpackT[((size_t)b * 32 + (t_begin >> 6)) * S + s0 + tid];
        linv_s[0][tid] = linv[(size_t)b * S + t_begin + tid];
    }
    __syncthreads();

    short8 QB[4][2];
    #pragma unroll
    for (int sf = 0; sf < 4; ++sf)
        #pragma unroll
        for (int kh = 0; kh < 2; ++kh)
            QB[sf][kh] = *(const short8*)&qsb[swz(sf * 16 + l, kh * 64 + hh * 16)];

    f32x4 oacc[4];
    #pragma unroll
    for (int df = 0; df < 4; ++df) oacc[df] = (f32x4){0.f, 0.f, 0.f, 0.f};

    for (int i = 0; i < niter; ++i) {
        const int cur = i & 1, nxt = cur ^ 1;
        const int t0 = t_begin + i * 64;

        // ---- phase A: C'[t][s] = mfma(A=K[t][d], B=Q[d][s]); LDS/VALU only
        short8 KA0 = *(const short8*)&ksb[cur][swz(16 * w + l, 0  + hh * 16)];
        short8 KA1 = *(const short8*)&ksb[cur][swz(16 * w + l, 64 + hh * 16)];
        float lv[4];
        #pragma unroll
        for (int r = 0; r < 4; ++r) lv[r] = linv_s[cur][16 * w + 4 * hh + r];

        #pragma unroll
        for (int sf = 0; sf < 4; ++sf) {
            f32x4 c4 = {0.f, 0.f, 0.f, 0.f};
            c4 = mfma16(KA0, QB[sf][0], c4);
            c4 = mfma16(KA1, QB[sf][1], c4);
            // lane: col s = sf*16+l ; rows t = 16w+4hh+r
            const unsigned long long bits = mrow2[cur][sf * 16 + l];
            float pv[4];
            #pragma unroll
            for (int r = 0; r < 4; ++r) {
                const int tloc = 16 * w + 4 * hh + r;
                pv[r] = ((bits >> tloc) & 1ull) ? 0.f : __expf(c4[r] * SCALE) * lv[r];
            }
            const int row = sf * 16 + l;
            const int cb = (32 * w + 8 * hh);
            *(uint2*)&ptb[row * 128 + (cb ^ ((row & 7) << 4))] =
                make_uint2(pack2(pv[0], pv[1]), pack2(pv[2], pv[3]));
        }
        __syncthreads(); // A->B: ptb visible; no VMEM issued since loop-end -> cheap

        // ---- issue next tile's staging (covered by phase B MFMAs)
        if (i + 1 < niter) {
            const int tn = t0 + 64;
            stage_tile((const char*)(kT + ((size_t)b * S + tn) * 64), 128, ksb[nxt], tid);
            stage_tile((const char*)(vb + (size_t)b * D * S + tn), (size_t)S * 2, vsb[nxt], tid);
            if (tid < 64) {
                const unsigned long long mw =
                    mpackT[((size_t)b * 32 + (tn >> 6)) * S + s0 + tid];
                const float lw = linv[(size_t)b * S + tn + tid];
                mrow2[nxt][tid]  = mw;
                linv_s[nxt][tid] = lw;
            }
        }

        // ---- phase B: out[s][d] += P[s][t] V^T[t][d]
        short8 PA0 = *(const short8*)&ptb[swz(16 * w + l, 0  + hh * 16)];
        short8 PA1 = *(const short8*)&ptb[swz(16 * w + l, 64 + hh * 16)];
        #pragma unroll
        for (int df = 0; df < 4; ++df) {
            short8 VB0 = *(const short8*)&vsb[cur][swz(df * 16 + l, 0  + hh * 16)];
            short8 VB1 = *(const short8*)&vsb[cur][swz(df * 16 + l, 64 + hh * 16)];
            oacc[df] = mfma16(PA0, VB0, oacc[df]);
            oacc[df] = mfma16(PA1, VB1, oacc[df]);
        }
        __syncthreads(); // loop-end: drains next-tile staging (covered by B)
    }

    #pragma unroll
    for (int df = 0; df < 4; ++df)
        #pragma unroll
        for (int r = 0; r < 4; ++r)
            outp[((size_t)b * S + s0 + 16 * w + 4 * hh + r) * D + df * 16 + l] = oacc[df][r];
}

__global__ void opart_reduce_kernel(const float* __restrict__ p, float* __restrict__ out)
{
    const size_t i = ((size_t)blockIdx.x * 256 + threadIdx.x) * 4;
    float4 a = *(const float4*)(p + i);
    float4 b = *(const float4*)(p + (size_t)B * S * D + i);
    *(float4*)(out + i) = make_float4(a.x + b.x, a.y + b.y, a.z + b.z, a.w + b.w);
}

// ===========================================================================
// Round-3 kernels (tier 3: ws >= 13.2MB but < 21.6MB) — raw mask
// ===========================================================================
__global__ __launch_bounds__(256, 2)
void transpose_cvt_kernel(const float* __restrict__ q, const float* __restrict__ k,
                          uint16_t* __restrict__ qT, uint16_t* __restrict__ kT)
{
    __shared__ float ts[64][65];
    const int tid = threadIdx.x;
    const int s0 = blockIdx.x * 64;
    const int b  = blockIdx.y;
    const float* src = blockIdx.z ? k : q;
    uint16_t*    dst = blockIdx.z ? kT : qT;
    {
        const int d = tid >> 2, c = tid & 3;
        const float* row = src + ((size_t)b * D + d) * S + s0 + c * 16;
        #pragma unroll
        for (int i = 0; i < 4; ++i) {
            float4 v4 = *(const float4*)(row + 4 * i);
            ts[c * 16 + 4 * i + 0][d] = v4.x;
            ts[c * 16 + 4 * i + 1][d] = v4.y;
            ts[c * 16 + 4 * i + 2][d] = v4.z;
            ts[c * 16 + 4 * i + 3][d] = v4.w;
        }
    }
    __syncthreads();
    {
        const int srow = tid >> 2, p = tid & 3;
        uint16_t tmp[16];
        #pragma unroll
        for (int j = 0; j < 16; ++j) tmp[j] = f2bf(ts[srow][p * 16 + j]);
        uint16_t* drow = dst + ((size_t)b * S + s0 + srow) * 64 + p * 16;
        *(uint4*)drow       = ((const uint4*)tmp)[0];
        *((uint4*)drow + 1) = ((const uint4*)tmp)[1];
    }
}

__global__ void cvt_v_kernel(const float* __restrict__ v, uint16_t* __restrict__ vb)
{
    const size_t i = ((size_t)blockIdx.x * 256 + threadIdx.x) * 4;
    float4 v4 = *(const float4*)(v + i);
    uint16_t t4[4] = {f2bf(v4.x), f2bf(v4.y), f2bf(v4.z), f2bf(v4.w)};
    *(uint2*)(vb + i) = *(const uint2*)t4;
}

__global__ __launch_bounds__(256, 2)
void pass1_old_kernel(const uint16_t* __restrict__ qT, const uint16_t* __restrict__ kT,
                      const void* __restrict__ mask, const int* __restrict__ flagp,
                      float* __restrict__ lpart)
{
    __shared__ __align__(16) unsigned char ksb[64 * 128];
    __shared__ __align__(16) unsigned char qsb[64 * 128];
    __shared__ float red[4][64];
    const int tid = threadIdx.x;
    const int lane = tid & 63, w = tid >> 6;
    const int l = lane & 15, hh = lane >> 4;
    const int t0 = blockIdx.x * 64;
    const int chunk = blockIdx.y;
    const int b = blockIdx.z;
    const int mode = *flagp;
    const size_t mbase = (size_t)b * S * S;

    stage_tile((const char*)(kT + ((size_t)b * S + t0) * 64), 128, ksb, tid);
    __syncthreads();
    short8 BF[4][2];
    #pragma unroll
    for (int tf = 0; tf < 4; ++tf)
        #pragma unroll
        for (int kh = 0; kh < 2; ++kh)
            BF[tf][kh] = *(const short8*)&ksb[swz(tf * 16 + l, kh * 64 + hh * 16)];
    float colacc[4] = {0.f, 0.f, 0.f, 0.f};
    for (int it = 0; it < 8; ++it) {
        const int sbase = chunk * 512 + it * 64;
        __syncthreads();
        stage_tile((const char*)(qT + ((size_t)b * S + sbase) * 64), 128, qsb, tid);
        __syncthreads();
        short8 A0 = *(const short8*)&qsb[swz(16 * w + l, 0  + hh * 16)];
        short8 A1 = *(const short8*)&qsb[swz(16 * w + l, 64 + hh * 16)];
        #pragma unroll
        for (int tf = 0; tf < 4; ++tf) {
            f32x4 c4 = {0.f, 0.f, 0.f, 0.f};
            c4 = mfma16(A0, BF[tf][0], c4);
            c4 = mfma16(A1, BF[tf][1], c4);
            const int t = t0 + tf * 16 + l;
            const int srow = sbase + 16 * w + 4 * hh;
            #pragma unroll
            for (int r = 0; r < 4; ++r)
                if (!mask_at(mask, mode, mbase + (size_t)(srow + r) * S + t))
                    colacc[tf] += __expf(c4[r] * SCALE);
        }
    }
    #pragma unroll
    for (int tf = 0; tf < 4; ++tf) {
        colacc[tf] += __shfl_xor(colacc[tf], 16);
        colacc[tf] += __shfl_xor(colacc[tf], 32);
    }
    if (lane < 16) {
        #pragma unroll
        for (int tf = 0; tf < 4; ++tf) red[w][tf * 16 + lane] = colacc[tf];
    }
    __syncthreads();
    if (tid < 64) {
        const float s = red[0][tid] + red[1][tid] + red[2][tid] + red[3][tid];
        lpart[(size_t)chunk * (B * S) + (size_t)b * S + t0 + tid] = s;
    }
}

__global__ __launch_bounds__(256, 2)
void pass2_old_kernel(const uint16_t* __restrict__ qT, const uint16_t* __restrict__ kT,
                      const uint16_t* __restrict__ vb, const void* __restrict__ mask,
                      const int* __restrict__ flagp, const float* __restrict__ linv,
                      float* __restrict__ out)
{
    __shared__ __align__(16) unsigned char qsb[64 * 128];
    __shared__ __align__(16) unsigned char ksb[64 * 128];
    __shared__ __align__(16) unsigned char vsb[64 * 128];
    __shared__ __align__(16) unsigned char ptb[64 * 128];
    __shared__ unsigned short mbits[64][4];
    __shared__ float linv_s[64];
    const int tid = threadIdx.x;
    const int lane = tid & 63, w = tid >> 6;
    const int l = lane & 15, hh = lane >> 4;
    const int s0 = blockIdx.x * 64;
    const int b = blockIdx.y;
    const int mode = *flagp;
    const size_t mbase = (size_t)b * S * S;

    stage_tile((const char*)(qT + ((size_t)b * S + s0) * 64), 128, qsb, tid);
    __syncthreads();
    short8 QB[4][2];
    #pragma unroll
    for (int sf = 0; sf < 4; ++sf)
        #pragma unroll
        for (int kh = 0; kh < 2; ++kh)
            QB[sf][kh] = *(const short8*)&qsb[swz(sf * 16 + l, kh * 64 + hh * 16)];
    f32x4 oacc[4];
    #pragma unroll
    for (int df = 0; df < 4; ++df) oacc[df] = (f32x4){0.f, 0.f, 0.f, 0.f};

    for (int t0 = 0; t0 < S; t0 += 64) {
        stage_tile((const char*)(kT + ((size_t)b * S + t0) * 64), 128, ksb, tid);
        stage_tile((const char*)(vb + (size_t)b * D * S + t0), (size_t)S * 2, vsb, tid);
        {
            const int srow = tid >> 2, c = tid & 3;
            const size_t base = mbase + (size_t)(s0 + srow) * S + t0 + c * 16;
            unsigned int bits = 0;
            #pragma unroll
            for (int j = 0; j < 16; ++j)
                bits |= (mask_at(mask, mode, base + j) ? 1u : 0u) << j;
            mbits[srow][c] = (unsigned short)bits;
        }
        if (tid < 64) linv_s[tid] = linv[(size_t)b * S + t0 + tid];
        __syncthreads();

        short8 KA0 = *(const short8*)&ksb[swz(16 * w + l, 0  + hh * 16)];
        short8 KA1 = *(const short8*)&ksb[swz(16 * w + l, 64 + hh * 16)];
        float lv[4];
        #pragma unroll
        for (int r = 0; r < 4; ++r) lv[r] = linv_s[16 * w + 4 * hh + r];
        #pragma unroll
        for (int sf = 0; sf < 4; ++sf) {
            f32x4 c4 = {0.f, 0.f, 0.f, 0.f};
            c4 = mfma16(KA0, QB[sf][0], c4);
            c4 = mfma16(KA1, QB[sf][1], c4);
            const unsigned int mb = (unsigned int)mbits[sf * 16 + l][w] >> (4 * hh);
            float pv[4];
            #pragma unroll
            for (int r = 0; r < 4; ++r)
                pv[r] = ((mb >> r) & 1u) ? 0.f : __expf(c4[r] * SCALE) * lv[r];
            const int row = sf * 16 + l;
            const int cb = (32 * w + 8 * hh);
            *(uint2*)&ptb[row * 128 + (cb ^ ((row & 7) << 4))] =
                make_uint2(pack2(pv[0], pv[1]), pack2(pv[2], pv[3]));
        }
        __syncthreads();
        short8 PA0 = *(const short8*)&ptb[swz(16 * w + l, 0  + hh * 16)];
        short8 PA1 = *(const short8*)&ptb[swz(16 * w + l, 64 + hh * 16)];
        #pragma unroll
        for (int df = 0; df < 4; ++df) {
            short8 VB0 = *(const short8*)&vsb[swz(df * 16 + l, 0  + hh * 16)];
            short8 VB1 = *(const short8*)&vsb[swz(df * 16 + l, 64 + hh * 16)];
            oacc[df] = mfma16(PA0, VB0, oacc[df]);
            oacc[df] = mfma16(PA1, VB1, oacc[df]);
        }
        __syncthreads();
    }
    #pragma unroll
    for (int df = 0; df < 4; ++df)
        #pragma unroll
        for (int r = 0; r < 4; ++r)
            out[((size_t)b * S + s0 + 16 * w + 4 * hh + r) * D + df * 16 + l] = oacc[df][r];
}

// ===========================================================================
// fp32 fallback (tiny ws)
// ===========================================================================
__global__ __launch_bounds__(256, 2)
void colsum_fb(const float* __restrict__ q, const float* __restrict__ k,
               const void* __restrict__ mask, const int* __restrict__ flagp,
               float* __restrict__ lsums)
{
    __shared__ __align__(16) float qs[128][68];
    __shared__ __align__(16) float ks[64][68];
    __shared__ float lred[32][66];
    const int tid = threadIdx.x;
    const int b = blockIdx.y;
    const int t0 = blockIdx.x * 64;
    const int mode = *flagp;
    {
        const int tl = tid & 63, d0 = tid >> 6;
        #pragma unroll
        for (int i = 0; i < 16; ++i) { const int d = d0 + i * 4; ks[tl][d] = k[(b * D + d) * S + t0 + tl]; }
    }
    const int tq = tid & 7, sq = tid >> 3;
    float lacc[8];
    #pragma unroll
    for (int j = 0; j < 8; ++j) lacc[j] = 0.f;
    const size_t mbase = (size_t)b * S * S;
    for (int s0 = 0; s0 < S; s0 += 128) {
        __syncthreads();
        {
            const int sl = tid & 127, d0 = tid >> 7;
            #pragma unroll
            for (int i = 0; i < 32; ++i) { const int d = d0 + i * 2; qs[sl][d] = q[(b * D + d) * S + s0 + sl]; }
        }
        __syncthreads();
        float acc[4][8];
        #pragma unroll
        for (int jj = 0; jj < 4; ++jj)
            #pragma unroll
            for (int j = 0; j < 8; ++j) acc[jj][j] = 0.f;
        #pragma unroll
        for (int dblk = 0; dblk < 16; ++dblk) {
            float4 q4[4];
            #pragma unroll
            for (int jj = 0; jj < 4; ++jj) q4[jj] = *(const float4*)&qs[sq + 32 * jj][dblk * 4];
            #pragma unroll
            for (int j = 0; j < 8; ++j) {
                const float4 k4 = *(const float4*)&ks[tq + 8 * j][dblk * 4];
                #pragma unroll
                for (int jj = 0; jj < 4; ++jj)
                    acc[jj][j] += q4[jj].x * k4.x + q4[jj].y * k4.y + q4[jj].z * k4.z + q4[jj].w * k4.w;
            }
        }
        #pragma unroll
        for (int jj = 0; jj < 4; ++jj) {
            const int sg = s0 + sq + 32 * jj;
            const size_t ridx = mbase + (size_t)sg * S + t0;
            #pragma unroll
            for (int j = 0; j < 8; ++j)
                if (!mask_at(mask, mode, ridx + tq + 8 * j)) lacc[j] += __expf(acc[jj][j] * SCALE);
        }
    }
    __syncthreads();
    #pragma unroll
    for (int j = 0; j < 8; ++j) lred[sq][tq + 8 * j] = lacc[j];
    __syncthreads();
    if (tid < 64) {
        float s = 0.f;
        #pragma unroll
        for (int i = 0; i < 32; ++i) s += lred[i][tid];
        lsums[b * S + t0 + tid] = s;
    }
}

__global__ __launch_bounds__(256, 2)
void attn_out_fb(const float* __restrict__ q, const float* __restrict__ k,
                 const float* __restrict__ v, const void* __restrict__ mask,
                 const int* __restrict__ flagp, const float* __restrict__ lsums,
                 float* __restrict__ out)
{
    __shared__ __align__(16) float qs[64][68];
    __shared__ __align__(16) float kw[64][68];
    __shared__ __align__(16) float pt[64][68];
    __shared__ float linv_sh[64];
    const int tid = threadIdx.x;
    const int b = blockIdx.y;
    const int s0 = blockIdx.x * 64;
    const int mode = *flagp;
    {
        const int sl = tid & 63, d0 = tid >> 6;
        #pragma unroll
        for (int i = 0; i < 16; ++i) { const int d = d0 + i * 4; qs[sl][d] = q[(b * D + d) * S + s0 + sl]; }
    }
    const int tq = tid & 7, sq = tid >> 3;
    float oacc[2][8];
    #pragma unroll
    for (int jj = 0; jj < 2; ++jj)
        #pragma unroll
        for (int dd = 0; dd < 8; ++dd) oacc[jj][dd] = 0.f;
    const size_t mbase = (size_t)b * S * S;
    for (int t0 = 0; t0 < S; t0 += 64) {
        __syncthreads();
        if (tid < 64) linv_sh[tid] = 1.f / lsums[b * S + t0 + tid];
        {
            const int tl = tid & 63, d0 = tid >> 6;
            #pragma unroll
            for (int i = 0; i < 16; ++i) { const int d = d0 + i * 4; kw[tl][d] = k[(b * D + d) * S + t0 + tl]; }
        }
        __syncthreads();
        float sc[2][8];
        #pragma unroll
        for (int jj = 0; jj < 2; ++jj)
            #pragma unroll
            for (int j = 0; j < 8; ++j) sc[jj][j] = 0.f;
        #pragma unroll
        for (int dblk = 0; dblk < 16; ++dblk) {
            float4 q4[2];
            #pragma unroll
            for (int jj = 0; jj < 2; ++jj) q4[jj] = *(const float4*)&qs[sq + 32 * jj][dblk * 4];
            #pragma unroll
            for (int j = 0; j < 8; ++j) {
                const float4 k4 = *(const float4*)&kw[tq + 8 * j][dblk * 4];
                #pragma unroll
                for (int jj = 0; jj < 2; ++jj)
                    sc[jj][j] += q4[jj].x * k4.x + q4[jj].y * k4.y + q4[jj].z * k4.z + q4[jj].w * k4.w;
            }
        }
        #pragma unroll
        for (int jj = 0; jj < 2; ++jj) {
            const int sg = s0 + sq + 32 * jj;
            const size_t ridx = mbase + (size_t)sg * S + t0;
            #pragma unroll
            for (int j = 0; j < 8; ++j) {
                const int tl = tq + 8 * j;
                const bool msk = mask_at(mask, mode, ridx + tl);
                pt[tl][sq + 32 * jj] = msk ? 0.f : __expf(sc[jj][j] * SCALE) * linv_sh[tl];
            }
        }
        __syncthreads();
        {
            const int tl = tid & 63, d0 = tid >> 6;
            #pragma unroll
            for (int i = 0; i < 16; ++i) { const int d = d0 + i * 4; kw[tl][d] = v[(b * D + d) * S + t0 + tl]; }
        }
        __syncthreads();
        #pragma unroll 8
        for (int t = 0; t < 64; ++t) {
            const float2 p2 = *(const float2*)&pt[t][sq * 2];
            const float4 w0 = *(const float4*)&kw[t][tq * 8];
            const float4 w1 = *(const float4*)&kw[t][tq * 8 + 4];
            oacc[0][0] += p2.x * w0.x; oacc[0][1] += p2.x * w0.y; oacc[0][2] += p2.x * w0.z; oacc[0][3] += p2.x * w0.w;
            oacc[0][4] += p2.x * w1.x; oacc[0][5] += p2.x * w1.y; oacc[0][6] += p2.x * w1.z; oacc[0][7] += p2.x * w1.w;
            oacc[1][0] += p2.y * w0.x; oacc[1][1] += p2.y * w0.y; oacc[1][2] += p2.y * w0.z; oacc[1][3] += p2.y * w0.w;
            oacc[1][4] += p2.y * w1.x; oacc[1][5] += p2.y * w1.y; oacc[1][6] += p2.y * w1.z; oacc[1][7] += p2.y * w1.w;
        }
    }
    #pragma unroll
    for (int jj = 0; jj < 2; ++jj) {
        float* dst = out + ((size_t)(b * S + s0 + sq * 2 + jj)) * D + tq * 8;
        *(float4*)dst = make_float4(oacc[jj][0], oacc[jj][1], oacc[jj][2], oacc[jj][3]);
        *(float4*)(dst + 4) = make_float4(oacc[jj][4], oacc[jj][5], oacc[jj][6], oacc[jj][7]);
    }
}

extern "C" void kernel_launch(void* const* d_in, const int* in_sizes, int n_in,
                              void* d_out, int out_size, void* d_ws, size_t ws_size,
                              hipStream_t stream) {
    const float* q = (const float*)d_in[0];
    const float* k = (const float*)d_in[1];
    const float* v = (const float*)d_in[2];
    const void*  mask = d_in[3];
    float* out = (float*)d_out;
    char* ws = (char*)d_ws;

    int* flag = (int*)(ws + WS_FLAG);
    probe_mask_kernel<<<1, 256, 0, stream>>>((const unsigned char*)mask, flag);

    if (ws_size >= NEED_T1) {
        float*    linv  = (float*)(ws + WS_LINV);
        float*    lpart = (float*)(ws + WS_LPART);
        uint16_t* qT    = (uint16_t*)(ws + WS_QT);
        uint16_t* kT    = (uint16_t*)(ws + WS_KT);
        uint16_t* vb    = (uint16_t*)(ws + WS_VB);
        unsigned long long* mpackT = (unsigned long long*)(ws + WS_MPACK);

        prep_kernel<<<dim3(S / 64, B, 3), 256, 0, stream>>>(q, k, v, qT, kT, vb);
        pass1_kernel<<<dim3(S / 64, 4, B), 256, 0, stream>>>(qT, kT, mask, flag, lpart, mpackT);
        linv_kernel<<<(B * S) / 256, 256, 0, stream>>>(lpart, linv);

        if (ws_size >= NEED_T2) {
            float* opart = (float*)(ws + WS_OPART);
            pass2_kernel<<<dim3(S / 64, 2, B), 256, 0, stream>>>(
                qT, kT, vb, mpackT, linv, opart, S / 2);
            opart_reduce_kernel<<<(B * S * D) / (256 * 4), 256, 0, stream>>>(opart, out);
        } else {
            pass2_kernel<<<dim3(S / 64, 1, B), 256, 0, stream>>>(
                qT, kT, vb, mpackT, linv, out, S);
        }
    } else if (ws_size >= NEED_OLD) {
        float*    linv  = (float*)(ws + WS_LINV);
        float*    lpart = (float*)(ws + WS_LPART);
        uint16_t* qT    = (uint16_t*)(ws + WS_QT);
        uint16_t* kT    = (uint16_t*)(ws + WS_KT);
        uint16_t* vb    = (uint16_t*)(ws + WS_VB);
        transpose_cvt_kernel<<<dim3(S / 64, B, 2), 256, 0, stream>>>(q, k, qT, kT);
        cvt_v_kernel<<<(B * D * S) / (256 * 4), 256, 0, stream>>>(v, vb);
        pass1_old_kernel<<<dim3(S / 64, 4, B), 256, 0, stream>>>(qT, kT, mask, flag, lpart);
        linv_kernel<<<(B * S) / 256, 256, 0, stream>>>(lpart, linv);
        pass2_old_kernel<<<dim3(S / 64, B), 256, 0, stream>>>(qT, kT, vb, mask, flag, linv, out);
    } else {
        float* lsums = (float*)(ws + WS_LINV);
        dim3 grid(S / 64, B);
        colsum_fb<<<grid, 256, 0, stream>>>(q, k, mask, flag, lsums);
        attn_out_fb<<<grid, 256, 0, stream>>>(q, k, v, mask, flag, lsums, out);
    }
}

// Round 8
// 169.406 us; speedup vs baseline: 1.0635x; 1.0635x over previous
//
#include <hip/hip_runtime.h>
#include <hip/hip_bf16.h>
#include <stdint.h>

// B=16, D=64, S=2048
// scores[b,s,t] = dot(q[b,:,s],k[b,:,t])/8 ; mask -> -1000 ; softmax over s
// (query axis) ; out[b,s,d] = sum_t attn[b,s,t] v[b,d,t].
// |score|<~6: p = mask?0:exp(score/8); l[t]=sum_s p; out = (p/l) @ V^T.
//
// Round-8:
//   prep (probe fused into one block): q,k transpose-cvt -> bf16; v cvt
//   pass1: MFMA colsums + inline mask pack -> lpart + mpackT
//          (A-frags read before MID barrier so it+1 staging is MFMA-covered)
//   pass2: s-split (32 rows/block) over ALL t; single-buffer K/V with
//          staggered prefetch; linv computed inline from lpart; direct out.
// 3 launches total on the fast path. Tiers: >=21.6MB full; >=13.2MB round-3
// path; else fp32 fallback.

namespace {
constexpr int B = 16;
constexpr int D = 64;
constexpr int S = 2048;
constexpr float SCALE = 0.125f;

typedef __attribute__((ext_vector_type(8))) short short8; // 8 bf16
typedef __attribute__((ext_vector_type(4))) float f32x4;

constexpr size_t WS_FLAG  = 0;
constexpr size_t WS_LINV  = 256;                    // B*S f32 (old tier)
constexpr size_t WS_LPART = 256 + 131072;           // 4*B*S f32
constexpr size_t WS_QT    = 655616;                 // B*S*D bf16 = 4MB
constexpr size_t WS_KT    = 4849920;
constexpr size_t WS_VB    = 9044224;
constexpr size_t WS_MPACK = 13238528;               // B*(S/64)*S u64 = 8MB
constexpr size_t NEED_OLD = 13238528;
constexpr size_t NEED_T1  = 21627136;
}

__device__ __forceinline__ bool mask_at(const void* mask, int mode, size_t idx) {
    if (mode == 1) return ((const int*)mask)[idx] != 0;
    if (mode == 2) return ((const float*)mask)[idx] != 0.0f;
    return ((const unsigned char*)mask)[idx] != 0;
}

__device__ __forceinline__ uint16_t f2bf(float f) {
    unsigned int u = __float_as_uint(f);
    unsigned int r = (u + 0x7fffu + ((u >> 16) & 1u)) >> 16;
    return (uint16_t)r;
}
__device__ __forceinline__ unsigned int pack2(float a, float b) {
    return (unsigned int)f2bf(a) | ((unsigned int)f2bf(b) << 16);
}

// swizzled LDS byte address for 128B-row tiles
__device__ __forceinline__ int swz(int row, int colByte) {
    return row * 128 + (colByte ^ ((row & 7) << 4));
}

__device__ __forceinline__ void gll16(const void* g, void* l) {
    __builtin_amdgcn_global_load_lds(
        (const __attribute__((address_space(1))) void*)g,
        (__attribute__((address_space(3))) void*)l, 16, 0, 0);
}

// 64-row x 128B tile; LDS linear dest, source pre-swizzled (2 gll16/thread).
__device__ __forceinline__ void stage_tile(const char* srcRows, size_t rowStrideB,
                                           unsigned char* dst, int tid) {
    const int lane = tid & 63, w = tid >> 6;
    const int lrow = lane >> 3;
    const int slot = (lane & 7) ^ lrow;
    #pragma unroll
    for (int c = 0; c < 2; ++c) {
        const int row = 16 * w + 8 * c + lrow;
        gll16(srcRows + (size_t)row * rowStrideB + slot * 16,
              dst + (16 * w + 8 * c) * 128);
    }
}

// 32-row x 128B tile (1 gll16/thread).
__device__ __forceinline__ void stage_tile32(const char* srcRows, size_t rowStrideB,
                                             unsigned char* dst, int tid) {
    const int lane = tid & 63, w = tid >> 6;
    const int lrow = lane >> 3;
    const int slot = (lane & 7) ^ lrow;
    const int row = 8 * w + lrow;
    gll16(srcRows + (size_t)row * rowStrideB + slot * 16, dst + 8 * w * 128);
}

__device__ __forceinline__ f32x4 mfma16(short8 a, short8 b, f32x4 c) {
    return __builtin_amdgcn_mfma_f32_16x16x32_bf16(a, b, c, 0, 0, 0);
}

// ---------------------------------------------------------------------------
// probe body (used standalone for fallback tiers, and embedded in prep)
// ---------------------------------------------------------------------------
__device__ __forceinline__ void probe_body(const unsigned char* mask, int* flag,
                                           int tid, int* c0s, int* c123s) {
    if (tid == 0) { *c0s = 0; *c123s = 0; }
    __syncthreads();
    int c0 = 0, c123 = 0;
    for (int f = tid; f < 65536; f += 256) {
        const int nz = (mask[f] != 0) ? 1 : 0;
        if ((f & 3) == 0) c0 += nz; else c123 += nz;
    }
    atomicAdd(c0s, c0);
    atomicAdd(c123s, c123);
    __syncthreads();
    if (tid == 0) {
        int mode = 0;
        if (*c123s == 0) mode = 1;
        else if (*c0s == 0) mode = 2;
        *flag = mode;
    }
}

__global__ void probe_mask_kernel(const unsigned char* __restrict__ mask,
                                  int* __restrict__ flag)
{
    __shared__ int c0s, c123s;
    probe_body(mask, flag, threadIdx.x, &c0s, &c123s);
}

// ---------------------------------------------------------------------------
// prep: z=0 -> q->qT, z=1 -> k->kT (transpose+cvt); z=2 -> v->vb (cvt).
// Block (0,0,2) additionally probes the mask dtype -> flag.
// ---------------------------------------------------------------------------
__global__ __launch_bounds__(256, 2)
void prep_kernel(const float* __restrict__ q, const float* __restrict__ k,
                 const float* __restrict__ v,
                 uint16_t* __restrict__ qT, uint16_t* __restrict__ kT,
                 uint16_t* __restrict__ vb,
                 const unsigned char* __restrict__ mask, int* __restrict__ flag)
{
    __shared__ float ts[64][65];
    const int tid = threadIdx.x;
    const int s0 = blockIdx.x * 64;
    const int b  = blockIdx.y;

    if (blockIdx.z == 2) {
        const int d = tid >> 2, c = tid & 3;
        const float* row = v + ((size_t)b * D + d) * S + s0 + c * 16;
        uint16_t*   orow = vb + ((size_t)b * D + d) * S + s0 + c * 16;
        #pragma unroll
        for (int i = 0; i < 4; ++i) {
            float4 v4 = *(const float4*)(row + 4 * i);
            uint16_t t4[4] = {f2bf(v4.x), f2bf(v4.y), f2bf(v4.z), f2bf(v4.w)};
            *(uint2*)(orow + 4 * i) = *(const uint2*)t4;
        }
        if (blockIdx.x == 0 && blockIdx.y == 0) {
            __shared__ int c0s, c123s;
            probe_body(mask, flag, tid, &c0s, &c123s);
        }
        return;
    }

    const float* src = blockIdx.z ? k : q;
    uint16_t*    dst = blockIdx.z ? kT : qT;
    {
        const int d = tid >> 2, c = tid & 3;
        const float* row = src + ((size_t)b * D + d) * S + s0 + c * 16;
        #pragma unroll
        for (int i = 0; i < 4; ++i) {
            float4 v4 = *(const float4*)(row + 4 * i);
            ts[c * 16 + 4 * i + 0][d] = v4.x;
            ts[c * 16 + 4 * i + 1][d] = v4.y;
            ts[c * 16 + 4 * i + 2][d] = v4.z;
            ts[c * 16 + 4 * i + 3][d] = v4.w;
        }
    }
    __syncthreads();
    {
        const int srow = tid >> 2, p = tid & 3;
        uint16_t tmp[16];
        #pragma unroll
        for (int j = 0; j < 16; ++j) tmp[j] = f2bf(ts[srow][p * 16 + j]);
        uint16_t* drow = dst + ((size_t)b * S + s0 + srow) * 64 + p * 16;
        *(uint4*)drow       = ((const uint4*)tmp)[0];
        *((uint4*)drow + 1) = ((const uint4*)tmp)[1];
    }
}

// ---------------------------------------------------------------------------
// pass1: MFMA colsums + inline streaming mask pack. grid (S/64, 4, B).
// Single qsb buffer: A-frags are ds_read BEFORE the MID barrier, so the
// qsb staging + mask reg-loads for it+1 (issued after MID) are covered by
// the MFMA/exp phase and drained at the next TOP barrier.
// ---------------------------------------------------------------------------
__global__ __launch_bounds__(256, 4)
void pass1_kernel(const uint16_t* __restrict__ qT, const uint16_t* __restrict__ kT,
                  const void* __restrict__ mask, const int* __restrict__ flagp,
                  float* __restrict__ lpart, unsigned long long* __restrict__ mpackT)
{
    __shared__ __align__(16) unsigned char ksb[64 * 128];
    __shared__ __align__(16) unsigned char qsb[64 * 128];
    __shared__ unsigned short mbits[64][4]; // [s_row][t_quarter]
    __shared__ float red[4][64];

    const int tid = threadIdx.x;
    const int lane = tid & 63, w = tid >> 6;
    const int l = lane & 15, hh = lane >> 4;
    const int t0 = blockIdx.x * 64;
    const int chunk = blockIdx.y;
    const int b = blockIdx.z;
    const int mode = *flagp;

    const int row_m = tid >> 2, cq = tid & 3;
    const size_t mrow_base = ((size_t)b * S + row_m) * S + t0 + cq * 16; // + sbase*S

    int4  mr4[4]; // 4B-element modes
    uint4 mr1;    // 1B-element mode
    auto load_mtile = [&](int sbase) {
        if (mode != 0) {
            const int4* p = (const int4*)((const int*)mask + mrow_base + (size_t)sbase * S);
            mr4[0] = p[0]; mr4[1] = p[1]; mr4[2] = p[2]; mr4[3] = p[3];
        } else {
            mr1 = *(const uint4*)((const unsigned char*)mask + mrow_base + (size_t)sbase * S);
        }
    };
    auto pack_mtile = [&]() -> unsigned int {
        unsigned int bits = 0;
        if (mode != 0) {
            #pragma unroll
            for (int i = 0; i < 4; ++i) {
                bits |= (mr4[i].x ? 1u : 0u) << (4 * i + 0);
                bits |= (mr4[i].y ? 1u : 0u) << (4 * i + 1);
                bits |= (mr4[i].z ? 1u : 0u) << (4 * i + 2);
                bits |= (mr4[i].w ? 1u : 0u) << (4 * i + 3);
            }
        } else {
            const unsigned int u[4] = {mr1.x, mr1.y, mr1.z, mr1.w};
            #pragma unroll
            for (int c = 0; c < 4; ++c) {
                bits |= ((u[c] & 0x000000FFu) ? 1u : 0u) << (4 * c + 0);
                bits |= ((u[c] & 0x0000FF00u) ? 1u : 0u) << (4 * c + 1);
                bits |= ((u[c] & 0x00FF0000u) ? 1u : 0u) << (4 * c + 2);
                bits |= ((u[c] & 0xFF000000u) ? 1u : 0u) << (4 * c + 3);
            }
        }
        return bits;
    };

    // prologue: issue everything for it=0
    stage_tile((const char*)(kT + ((size_t)b * S + t0) * 64), 128, ksb, tid);
    stage_tile((const char*)(qT + ((size_t)b * S + chunk * 512) * 64), 128, qsb, tid);
    load_mtile(chunk * 512);

    float colacc[4] = {0.f, 0.f, 0.f, 0.f};

    for (int it = 0; it < 8; ++it) {
        const int sbase = chunk * 512 + it * 64;

        __syncthreads(); // TOP: drains qsb[it] staging + mask regs (covered by prev MFMA)

        const unsigned int bits = pack_mtile();
        mbits[row_m][cq] = (unsigned short)bits;

        // read this tile's A-frags NOW so qsb can be overwritten after MID
        short8 A0 = *(const short8*)&qsb[swz(16 * w + l, 0  + hh * 16)];
        short8 A1 = *(const short8*)&qsb[swz(16 * w + l, 64 + hh * 16)];

        __syncthreads(); // MID: mbits visible; all qsb ds_reads complete

        // coalesced packed-mask writeout
        if (tid < 64) {
            const unsigned long long word =
                (unsigned long long)mbits[tid][0]
                | ((unsigned long long)mbits[tid][1] << 16)
                | ((unsigned long long)mbits[tid][2] << 32)
                | ((unsigned long long)mbits[tid][3] << 48);
            mpackT[((size_t)b * 32 + (t0 >> 6)) * S + sbase + tid] = word;
        }

        // issue next tile's VMEM; the MFMA phase below covers the latency
        if (it < 7) {
            stage_tile((const char*)(qT + ((size_t)b * S + sbase + 64) * 64), 128, qsb, tid);
            load_mtile(sbase + 64);
        }

        const int srow_l = 16 * w + 4 * hh;
        #pragma unroll
        for (int tf = 0; tf < 4; ++tf) {
            const short8 B0 = *(const short8*)&ksb[swz(tf * 16 + l, 0  + hh * 16)];
            const short8 B1 = *(const short8*)&ksb[swz(tf * 16 + l, 64 + hh * 16)];
            f32x4 c4 = {0.f, 0.f, 0.f, 0.f};
            c4 = mfma16(A0, B0, c4);
            c4 = mfma16(A1, B1, c4);
            #pragma unroll
            for (int r = 0; r < 4; ++r) {
                if (!((mbits[srow_l + r][tf] >> l) & 1))
                    colacc[tf] += __expf(c4[r] * SCALE);
            }
        }
    }

    #pragma unroll
    for (int tf = 0; tf < 4; ++tf) {
        colacc[tf] += __shfl_xor(colacc[tf], 16);
        colacc[tf] += __shfl_xor(colacc[tf], 32);
    }
    __syncthreads();
    if (lane < 16) {
        #pragma unroll
        for (int tf = 0; tf < 4; ++tf) red[w][tf * 16 + lane] = colacc[tf];
    }
    __syncthreads();
    if (tid < 64) {
        const float s = red[0][tid] + red[1][tid] + red[2][tid] + red[3][tid];
        lpart[(size_t)chunk * (B * S) + (size_t)b * S + t0 + tid] = s;
    }
}

// ---------------------------------------------------------------------------
// pass2: grid (S/32, B), 256 threads (4 waves), 32 s-rows per block, all t.
// Single-buffered K/V with staggered prefetch:
//   V[i] issued at top of phase A of i   (drains at barrier1, covered by A)
//   K[i+1]+meta[i+1] issued after barrier1 (drains at barrier2, covered by B)
// linv computed inline from lpart. Direct out write (no partials).
// ---------------------------------------------------------------------------
__global__ __launch_bounds__(256, 4)
void pass2_kernel(const uint16_t* __restrict__ qT, const uint16_t* __restrict__ kT,
                  const uint16_t* __restrict__ vb,
                  const unsigned long long* __restrict__ mpackT,
                  const float* __restrict__ lpart, float* __restrict__ out)
{
    __shared__ __align__(16) unsigned char qsb[32 * 128];
    __shared__ __align__(16) unsigned char ksb[64 * 128];
    __shared__ __align__(16) unsigned char vsb[64 * 128];
    __shared__ __align__(16) unsigned char ptb[32 * 128];
    __shared__ unsigned long long mrow2[2][32];
    __shared__ float linv_s[2][64];

    const int tid = threadIdx.x;
    const int lane = tid & 63, w = tid >> 6;
    const int l = lane & 15, hh = lane >> 4;
    const int s0 = blockIdx.x * 32;
    const int b = blockIdx.y;

    auto load_meta = [&](int tile, int slot) {
        if (tid < 64) {
            const int t = tile * 64 + tid;
            const float s = lpart[(size_t)b * S + t]
                          + lpart[(size_t)(B * S) + b * S + t]
                          + lpart[(size_t)(2 * B * S) + b * S + t]
                          + lpart[(size_t)(3 * B * S) + b * S + t];
            linv_s[slot][tid] = 1.0f / s;
        } else if (tid < 96) {
            mrow2[slot][tid - 64] =
                mpackT[((size_t)b * 32 + tile) * S + s0 + (tid - 64)];
        }
    };

    // prologue: Q + K[0] + V[0] + meta[0]
    stage_tile32((const char*)(qT + ((size_t)b * S + s0) * 64), 128, qsb, tid);
    stage_tile((const char*)(kT + (size_t)b * S * 64), 128, ksb, tid);
    stage_tile((const char*)(vb + (size_t)b * D * S), (size_t)S * 2, vsb, tid);
    load_meta(0, 0);
    __syncthreads();

    // Q B-frags for swapped QK^T: B[k=d][n=s], n=l -> s = sf*16+l
    short8 QB[2][2];
    #pragma unroll
    for (int sf = 0; sf < 2; ++sf)
        #pragma unroll
        for (int kh = 0; kh < 2; ++kh)
            QB[sf][kh] = *(const short8*)&qsb[swz(sf * 16 + l, kh * 64 + hh * 16)];

    f32x4 oacc[2];
    oacc[0] = (f32x4){0.f, 0.f, 0.f, 0.f};
    oacc[1] = (f32x4){0.f, 0.f, 0.f, 0.f};

    const int sb = w & 1;   // phase B: s-band
    const int dh = w >> 1;  // phase B: d-half

    for (int i = 0; i < 32; ++i) {
        const int cur = i & 1, nxt = cur ^ 1;

        // stagger: V[i] staging issued here (vsb dead since barrier2 of i-1)
        if (i > 0)
            stage_tile((const char*)(vb + (size_t)b * D * S + i * 64),
                       (size_t)S * 2, vsb, tid);

        // ---- phase A: C'[t][s] = mfma(A=K[t][d], B=Q[d][s]); wave w: t-band 16w
        short8 KA0 = *(const short8*)&ksb[swz(16 * w + l, 0  + hh * 16)];
        short8 KA1 = *(const short8*)&ksb[swz(16 * w + l, 64 + hh * 16)];
        float lv[4];
        #pragma unroll
        for (int r = 0; r < 4; ++r) lv[r] = linv_s[cur][16 * w + 4 * hh + r];

        #pragma unroll
        for (int sf = 0; sf < 2; ++sf) {
            f32x4 c4 = {0.f, 0.f, 0.f, 0.f};
            c4 = mfma16(KA0, QB[sf][0], c4);
            c4 = mfma16(KA1, QB[sf][1], c4);
            // lane: col s = sf*16+l ; rows t = 16w+4hh+r
            const unsigned long long bits = mrow2[cur][sf * 16 + l];
            float pv[4];
            #pragma unroll
            for (int r = 0; r < 4; ++r) {
                const int tloc = 16 * w + 4 * hh + r;
                pv[r] = ((bits >> tloc) & 1ull) ? 0.f : __expf(c4[r] * SCALE) * lv[r];
            }
            const int row = sf * 16 + l;          // s-row of P tile
            const int cb = (32 * w + 8 * hh);     // t-byte
            *(uint2*)&ptb[row * 128 + (cb ^ ((row & 7) << 4))] =
                make_uint2(pack2(pv[0], pv[1]), pack2(pv[2], pv[3]));
        }
        __syncthreads(); // barrier1: drains V[i] staging (covered by A); ptb visible

        // issue K[i+1] + meta[i+1] (ksb dead: KA already in regs; covered by B)
        if (i + 1 < 32) {
            stage_tile((const char*)(kT + ((size_t)b * S + (i + 1) * 64) * 64),
                       128, ksb, tid);
            load_meta(i + 1, nxt);
        }

        // ---- phase B: out[s][d] += P[s][t] V^T[t][d]
        short8 PA0 = *(const short8*)&ptb[swz(sb * 16 + l, 0  + hh * 16)];
        short8 PA1 = *(const short8*)&ptb[swz(sb * 16 + l, 64 + hh * 16)];
        #pragma unroll
        for (int df = 0; df < 2; ++df) {
            const int drow = (dh * 2 + df) * 16 + l;
            short8 VB0 = *(const short8*)&vsb[swz(drow, 0  + hh * 16)];
            short8 VB1 = *(const short8*)&vsb[swz(drow, 64 + hh * 16)];
            oacc[df] = mfma16(PA0, VB0, oacc[df]);
            oacc[df] = mfma16(PA1, VB1, oacc[df]);
        }
        __syncthreads(); // barrier2: drains K[i+1] staging + meta (covered by B)
    }

    #pragma unroll
    for (int df = 0; df < 2; ++df)
        #pragma unroll
        for (int r = 0; r < 4; ++r)
            out[((size_t)b * S + s0 + sb * 16 + 4 * hh + r) * D
                + (dh * 2 + df) * 16 + l] = oacc[df][r];
}

// ===========================================================================
// Round-3 kernels (tier: ws >= 13.2MB but < 21.6MB) — raw mask
// ===========================================================================
__global__ __launch_bounds__(256, 2)
void transpose_cvt_kernel(const float* __restrict__ q, const float* __restrict__ k,
                          uint16_t* __restrict__ qT, uint16_t* __restrict__ kT)
{
    __shared__ float ts[64][65];
    const int tid = threadIdx.x;
    const int s0 = blockIdx.x * 64;
    const int b  = blockIdx.y;
    const float* src = blockIdx.z ? k : q;
    uint16_t*    dst = blockIdx.z ? kT : qT;
    {
        const int d = tid >> 2, c = tid & 3;
        const float* row = src + ((size_t)b * D + d) * S + s0 + c * 16;
        #pragma unroll
        for (int i = 0; i < 4; ++i) {
            float4 v4 = *(const float4*)(row + 4 * i);
            ts[c * 16 + 4 * i + 0][d] = v4.x;
            ts[c * 16 + 4 * i + 1][d] = v4.y;
            ts[c * 16 + 4 * i + 2][d] = v4.z;
            ts[c * 16 + 4 * i + 3][d] = v4.w;
        }
    }
    __syncthreads();
    {
        const int srow = tid >> 2, p = tid & 3;
        uint16_t tmp[16];
        #pragma unroll
        for (int j = 0; j < 16; ++j) tmp[j] = f2bf(ts[srow][p * 16 + j]);
        uint16_t* drow = dst + ((size_t)b * S + s0 + srow) * 64 + p * 16;
        *(uint4*)drow       = ((const uint4*)tmp)[0];
        *((uint4*)drow + 1) = ((const uint4*)tmp)[1];
    }
}

__global__ void cvt_v_kernel(const float* __restrict__ v, uint16_t* __restrict__ vb)
{
    const size_t i = ((size_t)blockIdx.x * 256 + threadIdx.x) * 4;
    float4 v4 = *(const float4*)(v + i);
    uint16_t t4[4] = {f2bf(v4.x), f2bf(v4.y), f2bf(v4.z), f2bf(v4.w)};
    *(uint2*)(vb + i) = *(const uint2*)t4;
}

__global__ void linv_kernel(const float* __restrict__ lpart, float* __restrict__ linv)
{
    const int i = blockIdx.x * 256 + threadIdx.x;
    const float s = lpart[i] + lpart[B * S + i] + lpart[2 * B * S + i] + lpart[3 * B * S + i];
    linv[i] = 1.0f / s;
}

__global__ __launch_bounds__(256, 2)
void pass1_old_kernel(const uint16_t* __restrict__ qT, const uint16_t* __restrict__ kT,
                      const void* __restrict__ mask, const int* __restrict__ flagp,
                      float* __restrict__ lpart)
{
    __shared__ __align__(16) unsigned char ksb[64 * 128];
    __shared__ __align__(16) unsigned char qsb[64 * 128];
    __shared__ float red[4][64];
    const int tid = threadIdx.x;
    const int lane = tid & 63, w = tid >> 6;
    const int l = lane & 15, hh = lane >> 4;
    const int t0 = blockIdx.x * 64;
    const int chunk = blockIdx.y;
    const int b = blockIdx.z;
    const int mode = *flagp;
    const size_t mbase = (size_t)b * S * S;

    stage_tile((const char*)(kT + ((size_t)b * S + t0) * 64), 128, ksb, tid);
    __syncthreads();
    short8 BF[4][2];
    #pragma unroll
    for (int tf = 0; tf < 4; ++tf)
        #pragma unroll
        for (int kh = 0; kh < 2; ++kh)
            BF[tf][kh] = *(const short8*)&ksb[swz(tf * 16 + l, kh * 64 + hh * 16)];
    float colacc[4] = {0.f, 0.f, 0.f, 0.f};
    for (int it = 0; it < 8; ++it) {
        const int sbase = chunk * 512 + it * 64;
        __syncthreads();
        stage_tile((const char*)(qT + ((size_t)b * S + sbase) * 64), 128, qsb, tid);
        __syncthreads();
        short8 A0 = *(const short8*)&qsb[swz(16 * w + l, 0  + hh * 16)];
        short8 A1 = *(const short8*)&qsb[swz(16 * w + l, 64 + hh * 16)];
        #pragma unroll
        for (int tf = 0; tf < 4; ++tf) {
            f32x4 c4 = {0.f, 0.f, 0.f, 0.f};
            c4 = mfma16(A0, BF[tf][0], c4);
            c4 = mfma16(A1, BF[tf][1], c4);
            const int t = t0 + tf * 16 + l;
            const int srow = sbase + 16 * w + 4 * hh;
            #pragma unroll
            for (int r = 0; r < 4; ++r)
                if (!mask_at(mask, mode, mbase + (size_t)(srow + r) * S + t))
                    colacc[tf] += __expf(c4[r] * SCALE);
        }
    }
    #pragma unroll
    for (int tf = 0; tf < 4; ++tf) {
        colacc[tf] += __shfl_xor(colacc[tf], 16);
        colacc[tf] += __shfl_xor(colacc[tf], 32);
    }
    if (lane < 16) {
        #pragma unroll
        for (int tf = 0; tf < 4; ++tf) red[w][tf * 16 + lane] = colacc[tf];
    }
    __syncthreads();
    if (tid < 64) {
        const float s = red[0][tid] + red[1][tid] + red[2][tid] + red[3][tid];
        lpart[(size_t)chunk * (B * S) + (size_t)b * S + t0 + tid] = s;
    }
}

__global__ __launch_bounds__(256, 2)
void pass2_old_kernel(const uint16_t* __restrict__ qT, const uint16_t* __restrict__ kT,
                      const uint16_t* __restrict__ vb, const void* __restrict__ mask,
                      const int* __restrict__ flagp, const float* __restrict__ linv,
                      float* __restrict__ out)
{
    __shared__ __align__(16) unsigned char qsb[64 * 128];
    __shared__ __align__(16) unsigned char ksb[64 * 128];
    __shared__ __align__(16) unsigned char vsb[64 * 128];
    __shared__ __align__(16) unsigned char ptb[64 * 128];
    __shared__ unsigned short mbits[64][4];
    __shared__ float linv_s[64];
    const int tid = threadIdx.x;
    const int lane = tid & 63, w = tid >> 6;
    const int l = lane & 15, hh = lane >> 4;
    const int s0 = blockIdx.x * 64;
    const int b = blockIdx.y;
    const int mode = *flagp;
    const size_t mbase = (size_t)b * S * S;

    stage_tile((const char*)(qT + ((size_t)b * S + s0) * 64), 128, qsb, tid);
    __syncthreads();
    short8 QB[4][2];
    #pragma unroll
    for (int sf = 0; sf < 4; ++sf)
        #pragma unroll
        for (int kh = 0; kh < 2; ++kh)
            QB[sf][kh] = *(const short8*)&qsb[swz(sf * 16 + l, kh * 64 + hh * 16)];
    f32x4 oacc[4];
    #pragma unroll
    for (int df = 0; df < 4; ++df) oacc[df] = (f32x4){0.f, 0.f, 0.f, 0.f};

    for (int t0 = 0; t0 < S; t0 += 64) {
        stage_tile((const char*)(kT + ((size_t)b * S + t0) * 64), 128, ksb, tid);
        stage_tile((const char*)(vb + (size_t)b * D * S + t0), (size_t)S * 2, vsb, tid);
        {
            const int srow = tid >> 2, c = tid & 3;
            const size_t base = mbase + (size_t)(s0 + srow) * S + t0 + c * 16;
            unsigned int bits = 0;
            #pragma unroll
            for (int j = 0; j < 16; ++j)
                bits |= (mask_at(mask, mode, base + j) ? 1u : 0u) << j;
            mbits[srow][c] = (unsigned short)bits;
        }
        if (tid < 64) linv_s[tid] = linv[(size_t)b * S + t0 + tid];
        __syncthreads();

        short8 KA0 = *(const short8*)&ksb[swz(16 * w + l, 0  + hh * 16)];
        short8 KA1 = *(const short8*)&ksb[swz(16 * w + l, 64 + hh * 16)];
        float lv[4];
        #pragma unroll
        for (int r = 0; r < 4; ++r) lv[r] = linv_s[16 * w + 4 * hh + r];
        #pragma unroll
        for (int sf = 0; sf < 4; ++sf) {
            f32x4 c4 = {0.f, 0.f, 0.f, 0.f};
            c4 = mfma16(KA0, QB[sf][0], c4);
            c4 = mfma16(KA1, QB[sf][1], c4);
            const unsigned int mb = (unsigned int)mbits[sf * 16 + l][w] >> (4 * hh);
            float pv[4];
            #pragma unroll
            for (int r = 0; r < 4; ++r)
                pv[r] = ((mb >> r) & 1u) ? 0.f : __expf(c4[r] * SCALE) * lv[r];
            const int row = sf * 16 + l;
            const int cb = (32 * w + 8 * hh);
            *(uint2*)&ptb[row * 128 + (cb ^ ((row & 7) << 4))] =
                make_uint2(pack2(pv[0], pv[1]), pack2(pv[2], pv[3]));
        }
        __syncthreads();
        short8 PA0 = *(const short8*)&ptb[swz(16 * w + l, 0  + hh * 16)];
        short8 PA1 = *(const short8*)&ptb[swz(16 * w + l, 64 + hh * 16)];
        #pragma unroll
        for (int df = 0; df < 4; ++df) {
            short8 VB0 = *(const short8*)&vsb[swz(df * 16 + l, 0  + hh * 16)];
            short8 VB1 = *(const short8*)&vsb[swz(df * 16 + l, 64 + hh * 16)];
            oacc[df] = mfma16(PA0, VB0, oacc[df]);
            oacc[df] = mfma16(PA1, VB1, oacc[df]);
        }
        __syncthreads();
    }
    #pragma unroll
    for (int df = 0; df < 4; ++df)
        #pragma unroll
        for (int r = 0; r < 4; ++r)
            out[((size_t)b * S + s0 + 16 * w + 4 * hh + r) * D + df * 16 + l] = oacc[df][r];
}

// ===========================================================================
// fp32 fallback (tiny ws)
// ===========================================================================
__global__ __launch_bounds__(256, 2)
void colsum_fb(const float* __restrict__ q, const float* __restrict__ k,
               const void* __restrict__ mask, const int* __restrict__ flagp,
               float* __restrict__ lsums)
{
    __shared__ __align__(16) float qs[128][68];
    __shared__ __align__(16) float ks[64][68];
    __shared__ float lred[32][66];
    const int tid = threadIdx.x;
    const int b = blockIdx.y;
    const int t0 = blockIdx.x * 64;
    const int mode = *flagp;
    {
        const int tl = tid & 63, d0 = tid >> 6;
        #pragma unroll
        for (int i = 0; i < 16; ++i) { const int d = d0 + i * 4; ks[tl][d] = k[(b * D + d) * S + t0 + tl]; }
    }
    const int tq = tid & 7, sq = tid >> 3;
    float lacc[8];
    #pragma unroll
    for (int j = 0; j < 8; ++j) lacc[j] = 0.f;
    const size_t mbase = (size_t)b * S * S;
    for (int s0 = 0; s0 < S; s0 += 128) {
        __syncthreads();
        {
            const int sl = tid & 127, d0 = tid >> 7;
            #pragma unroll
            for (int i = 0; i < 32; ++i) { const int d = d0 + i * 2; qs[sl][d] = q[(b * D + d) * S + s0 + sl]; }
        }
        __syncthreads();
        float acc[4][8];
        #pragma unroll
        for (int jj = 0; jj < 4; ++jj)
            #pragma unroll
            for (int j = 0; j < 8; ++j) acc[jj][j] = 0.f;
        #pragma unroll
        for (int dblk = 0; dblk < 16; ++dblk) {
            float4 q4[4];
            #pragma unroll
            for (int jj = 0; jj < 4; ++jj) q4[jj] = *(const float4*)&qs[sq + 32 * jj][dblk * 4];
            #pragma unroll
            for (int j = 0; j < 8; ++j) {
                const float4 k4 = *(const float4*)&ks[tq + 8 * j][dblk * 4];
                #pragma unroll
                for (int jj = 0; jj < 4; ++jj)
                    acc[jj][j] += q4[jj].x * k4.x + q4[jj].y * k4.y + q4[jj].z * k4.z + q4[jj].w * k4.w;
            }
        }
        #pragma unroll
        for (int jj = 0; jj < 4; ++jj) {
            const int sg = s0 + sq + 32 * jj;
            const size_t ridx = mbase + (size_t)sg * S + t0;
            #pragma unroll
            for (int j = 0; j < 8; ++j)
                if (!mask_at(mask, mode, ridx + tq + 8 * j)) lacc[j] += __expf(acc[jj][j] * SCALE);
        }
    }
    __syncthreads();
    #pragma unroll
    for (int j = 0; j < 8; ++j) lred[sq][tq + 8 * j] = lacc[j];
    __syncthreads();
    if (tid < 64) {
        float s = 0.f;
        #pragma unroll
        for (int i = 0; i < 32; ++i) s += lred[i][tid];
        lsums[b * S + t0 + tid] = s;
    }
}

__global__ __launch_bounds__(256, 2)
void attn_out_fb(const float* __restrict__ q, const float* __restrict__ k,
                 const float* __restrict__ v, const void* __restrict__ mask,
                 const int* __restrict__ flagp, const float* __restrict__ lsums,
                 float* __restrict__ out)
{
    __shared__ __align__(16) float qs[64][68];
    __shared__ __align__(16) float kw[64][68];
    __shared__ __align__(16) float pt[64][68];
    __shared__ float linv_sh[64];
    const int tid = threadIdx.x;
    const int b = blockIdx.y;
    const int s0 = blockIdx.x * 64;
    const int mode = *flagp;
    {
        const int sl = tid & 63, d0 = tid >> 6;
        #pragma unroll
        for (int i = 0; i < 16; ++i) { const int d = d0 + i * 4; qs[sl][d] = q[(b * D + d) * S + s0 + sl]; }
    }
    const int tq = tid & 7, sq = tid >> 3;
    float oacc[2][8];
    #pragma unroll
    for (int jj = 0; jj < 2; ++jj)
        #pragma unroll
        for (int dd = 0; dd < 8; ++dd) oacc[jj][dd] = 0.f;
    const size_t mbase = (size_t)b * S * S;
    for (int t0 = 0; t0 < S; t0 += 64) {
        __syncthreads();
        if (tid < 64) linv_sh[tid] = 1.f / lsums[b * S + t0 + tid];
        {
            const int tl = tid & 63, d0 = tid >> 6;
            #pragma unroll
            for (int i = 0; i < 16; ++i) { const int d = d0 + i * 4; kw[tl][d] = k[(b * D + d) * S + t0 + tl]; }
        }
        __syncthreads();
        float sc[2][8];
        #pragma unroll
        for (int jj = 0; jj < 2; ++jj)
            #pragma unroll
            for (int j = 0; j < 8; ++j) sc[jj][j] = 0.f;
        #pragma unroll
        for (int dblk = 0; dblk < 16; ++dblk) {
            float4 q4[2];
            #pragma unroll
            for (int jj = 0; jj < 2; ++jj) q4[jj] = *(const float4*)&qs[sq + 32 * jj][dblk * 4];
            #pragma unroll
            for (int j = 0; j < 8; ++j) {
                const float4 k4 = *(const float4*)&kw[tq + 8 * j][dblk * 4];
                #pragma unroll
                for (int jj = 0; jj < 2; ++jj)
                    sc[jj][j] += q4[jj].x * k4.x + q4[jj].y * k4.y + q4[jj].z * k4.z + q4[jj].w * k4.w;
            }
        }
        #pragma unroll
        for (int jj = 0; jj < 2; ++jj) {
            const int sg = s0 + sq + 32 * jj;
            const size_t ridx = mbase + (size_t)sg * S + t0;
            #pragma unroll
            for (int j = 0; j < 8; ++j) {
                const int tl = tq + 8 * j;
                const bool msk = mask_at(mask, mode, ridx + tl);
                pt[tl][sq + 32 * jj] = msk ? 0.f : __expf(sc[jj][j] * SCALE) * linv_sh[tl];
            }
        }
        __syncthreads();
        {
            const int tl = tid & 63, d0 = tid >> 6;
            #pragma unroll
            for (int i = 0; i < 16; ++i) { const int d = d0 + i * 4; kw[tl][d] = v[(b * D + d) * S + t0 + tl]; }
        }
        __syncthreads();
        #pragma unroll 8
        for (int t = 0; t < 64; ++t) {
            const float2 p2 = *(const float2*)&pt[t][sq * 2];
            const float4 w0 = *(const float4*)&kw[t][tq * 8];
            const float4 w1 = *(const float4*)&kw[t][tq * 8 + 4];
            oacc[0][0] += p2.x * w0.x; oacc[0][1] += p2.x * w0.y; oacc[0][2] += p2.x * w0.z; oacc[0][3] += p2.x * w0.w;
            oacc[0][4] += p2.x * w1.x; oacc[0][5] += p2.x * w1.y; oacc[0][6] += p2.x * w1.z; oacc[0][7] += p2.x * w1.w;
            oacc[1][0] += p2.y * w0.x; oacc[1][1] += p2.y * w0.y; oacc[1][2] += p2.y * w0.z; oacc[1][3] += p2.y * w0.w;
            oacc[1][4] += p2.y * w1.x; oacc[1][5] += p2.y * w1.y; oacc[1][6] += p2.y * w1.z; oacc[1][7] += p2.y * w1.w;
        }
    }
    #pragma unroll
    for (int jj = 0; jj < 2; ++jj) {
        float* dst = out + ((size_t)(b * S + s0 + sq * 2 + jj)) * D + tq * 8;
        *(float4*)dst = make_float4(oacc[jj][0], oacc[jj][1], oacc[jj][2], oacc[jj][3]);
        *(float4*)(dst + 4) = make_float4(oacc[jj][4], oacc[jj][5], oacc[jj][6], oacc[jj][7]);
    }
}

extern "C" void kernel_launch(void* const* d_in, const int* in_sizes, int n_in,
                              void* d_out, int out_size, void* d_ws, size_t ws_size,
                              hipStream_t stream) {
    const float* q = (const float*)d_in[0];
    const float* k = (const float*)d_in[1];
    const float* v = (const float*)d_in[2];
    const void*  mask = d_in[3];
    float* out = (float*)d_out;
    char* ws = (char*)d_ws;

    int* flag = (int*)(ws + WS_FLAG);

    if (ws_size >= NEED_T1) {
        float*    lpart = (float*)(ws + WS_LPART);
        uint16_t* qT    = (uint16_t*)(ws + WS_QT);
        uint16_t* kT    = (uint16_t*)(ws + WS_KT);
        uint16_t* vb    = (uint16_t*)(ws + WS_VB);
        unsigned long long* mpackT = (unsigned long long*)(ws + WS_MPACK);

        prep_kernel<<<dim3(S / 64, B, 3), 256, 0, stream>>>(
            q, k, v, qT, kT, vb, (const unsigned char*)mask, flag);
        pass1_kernel<<<dim3(S / 64, 4, B), 256, 0, stream>>>(
            qT, kT, mask, flag, lpart, mpackT);
        pass2_kernel<<<dim3(S / 32, B), 256, 0, stream>>>(
            qT, kT, vb, mpackT, lpart, out);
    } else if (ws_size >= NEED_OLD) {
        float*    linv  = (float*)(ws + WS_LINV);
        float*    lpart = (float*)(ws + WS_LPART);
        uint16_t* qT    = (uint16_t*)(ws + WS_QT);
        uint16_t* kT    = (uint16_t*)(ws + WS_KT);
        uint16_t* vb    = (uint16_t*)(ws + WS_VB);
        probe_mask_kernel<<<1, 256, 0, stream>>>((const unsigned char*)mask, flag);
        transpose_cvt_kernel<<<dim3(S / 64, B, 2), 256, 0, stream>>>(q, k, qT, kT);
        cvt_v_kernel<<<(B * D * S) / (256 * 4), 256, 0, stream>>>(v, vb);
        pass1_old_kernel<<<dim3(S / 64, 4, B), 256, 0, stream>>>(qT, kT, mask, flag, lpart);
        linv_kernel<<<(B * S) / 256, 256, 0, stream>>>(lpart, linv);
        pass2_old_kernel<<<dim3(S / 64, B), 256, 0, stream>>>(qT, kT, vb, mask, flag, linv, out);
    } else {
        float* lsums = (float*)(ws + WS_LINV);
        probe_mask_kernel<<<1, 256, 0, stream>>>((const unsigned char*)mask, flag);
        dim3 grid(S / 64, B);
        colsum_fb<<<grid, 256, 0, stream>>>(q, k, mask, flag, lsums);
        attn_out_fb<<<grid, 256, 0, stream>>>(q, k, v, mask, flag, lsums, out);
    }
}